// Round 6
// baseline (131.164 us; speedup 1.0000x reference)
//
#include <hip/hip_runtime.h>

// ADDA local attention, K=3, dilation=1, head_dim=64.
// q,k,v = [B=8, d=512, H=56, W=56] fp32 (channel-major), out = [B,H,W,512] fp32.
//
// R6 design (from R4/R5 counters: latency-bound, stores + barriers + lane
// layout were the costs):
//  - thread = (pixel PAIR, channel group cg in LOW 2 bits of tid)
//    -> logit reduce across 4 cg = two __shfl_xor steps, NO LDS, NO barriers
//  - float2 window loads, lanes with same cg are consecutive pairs ->
//    every load instr = fully-used 64B lines (2 lines x 4 planes)
//  - channel ownership interleaved c = 16m + 4cg + i -> stores are float4
//    where 4 adjacent cg lanes form one contiguous 64B line (zero inflation)
//  - softmax redundant in every lane (no serial section)
//  - per-m streaming accumulators keep VGPR low (target 8 waves/SIMD)

namespace {

constexpr int HD   = 64;
constexpr int HH   = 56, WW = 56, HW = HH * WW;   // 3136
constexpr int CS   = HW;                           // channel stride
constexpr int DTOT = 512;
constexpr float SCALE = 0.125f;                    // 64^-0.5
constexpr int PXT  = 128;                          // pixels per block tile
constexpr int NPT  = (HW + PXT - 1) / PXT;         // 25 (last tile half)

__global__ __launch_bounds__(256, 4)
void adda_fwd(const float* __restrict__ qg, const float* __restrict__ kg,
              const float* __restrict__ vg, float* __restrict__ outg) {
  const int tid = (int)threadIdx.x;
  const int cg  = tid & 3;        // channel group, low bits -> shfl_xor(1,2)
  const int pl  = tid >> 2;       // pair lane 0..63
  const int tile = blockIdx.x % NPT;
  const int bh   = blockIdx.x / NPT;     // b*8 + head

  const int p0 = tile * PXT + 2 * pl;    // even pixel index
  if (p0 >= HW) return;                  // tail tile (no barriers -> safe)

  const int y  = p0 / WW;
  const int x0 = p0 - y * WW;            // even, 0..54 (pair never crosses row)

  const int base = bh * (HD * HW) + p0;
  const float* __restrict__ qp = qg + base;
  const float* __restrict__ kp = kg + base;
  const float* __restrict__ vp = vg + base;

  // clamped row offsets; clamped horizontal f2 offsets (garbage reads are
  // only ever multiplied by weights that the valid-mask forces to zero)
  int ro[3];
#pragma unroll
  for (int r = 0; r < 3; ++r)
    ro[r] = ((unsigned)(y + r - 1) < (unsigned)HH) ? (r - 1) * WW : 0;
  const int xlo = (x0 == 0)  ? 0 : -2;   // f2 covering x0-2,x0-1
  const int xhi = (x0 == 54) ? 0 : 2;    // f2 covering x0+2,x0+3

  // ---- pass 1: partial logits (this thread's 16 channels: c=16m+4cg+i) ----
  float lg[2][9];
#pragma unroll
  for (int e = 0; e < 2; ++e)
#pragma unroll
    for (int n = 0; n < 9; ++n) lg[e][n] = 0.f;

#pragma unroll
  for (int m = 0; m < 4; ++m) {
#pragma unroll
    for (int i = 0; i < 4; ++i) {
      const int c = 16 * m + 4 * cg + i;
      const float2 qv = *(const float2*)(qp + c * CS);
      const float* kc = kp + c * CS;
#pragma unroll
      for (int r = 0; r < 3; ++r) {
        const float* rp = kc + ro[r];
        const float2 a  = *(const float2*)(rp + xlo);
        const float2 bm = *(const float2*)(rp);
        const float2 ch = *(const float2*)(rp + xhi);
        const float w1 = a.y, w2 = bm.x, w3 = bm.y, w4 = ch.x;
        lg[0][r*3+0] = fmaf(qv.x, w1, lg[0][r*3+0]);
        lg[0][r*3+1] = fmaf(qv.x, w2, lg[0][r*3+1]);
        lg[0][r*3+2] = fmaf(qv.x, w3, lg[0][r*3+2]);
        lg[1][r*3+0] = fmaf(qv.y, w2, lg[1][r*3+0]);
        lg[1][r*3+1] = fmaf(qv.y, w3, lg[1][r*3+1]);
        lg[1][r*3+2] = fmaf(qv.y, w4, lg[1][r*3+2]);
      }
    }
  }

  // ---- butterfly reduce across the 4 cg lanes (xor 1, 2) ----
#pragma unroll
  for (int e = 0; e < 2; ++e)
#pragma unroll
    for (int n = 0; n < 9; ++n) {
      float v = lg[e][n];
      v += __shfl_xor(v, 1);
      v += __shfl_xor(v, 2);
      lg[e][n] = v;
    }

  // ---- softmax per pixel, redundant in all lanes ----
  float w[2][9];
#pragma unroll
  for (int e = 0; e < 2; ++e) {
    const int xx = x0 + e;
    float lv[9];
    bool ok[9];
#pragma unroll
    for (int n = 0; n < 9; ++n) {
      const int dy = n / 3 - 1, dx = n % 3 - 1;
      ok[n] = ((unsigned)(y + dy) < (unsigned)HH) &&
              ((unsigned)(xx + dx) < (unsigned)WW);
      lv[n] = ok[n] ? lg[e][n] * SCALE : 0.f;  // zero-padded unfold: OOB = 0
    }
    float mx = lv[0];
#pragma unroll
    for (int n = 1; n < 9; ++n) mx = fmaxf(mx, lv[n]);
    float ex[9], sum = 0.f;
#pragma unroll
    for (int n = 0; n < 9; ++n) { ex[n] = __expf(lv[n] - mx); sum += ex[n]; }
    const float inv = 1.f / sum;
#pragma unroll
    for (int n = 0; n < 9; ++n)
      w[e][n] = ok[n] ? ex[n] * inv : 0.f;     // OOB v contributes zero
  }

  // ---- pass 2: weighted V, streamed per m-block, float4 stores ----
  const int b = bh >> 3, head = bh & 7;
  float* __restrict__ ob = outg + ((long)b * HW + p0) * DTOT + head * HD;

#pragma unroll
  for (int m = 0; m < 4; ++m) {
    float acc0[4], acc1[4];
#pragma unroll
    for (int i = 0; i < 4; ++i) { acc0[i] = 0.f; acc1[i] = 0.f; }
#pragma unroll
    for (int i = 0; i < 4; ++i) {
      const int c = 16 * m + 4 * cg + i;
      const float* vc = vp + c * CS;
#pragma unroll
      for (int r = 0; r < 3; ++r) {
        const float* rp = vc + ro[r];
        const float2 a  = *(const float2*)(rp + xlo);
        const float2 bm = *(const float2*)(rp);
        const float2 ch = *(const float2*)(rp + xhi);
        const float w1 = a.y, w2 = bm.x, w3 = bm.y, w4 = ch.x;
        acc0[i] = fmaf(w[0][r*3+0], w1, acc0[i]);
        acc0[i] = fmaf(w[0][r*3+1], w2, acc0[i]);
        acc0[i] = fmaf(w[0][r*3+2], w3, acc0[i]);
        acc1[i] = fmaf(w[1][r*3+0], w2, acc1[i]);
        acc1[i] = fmaf(w[1][r*3+1], w3, acc1[i]);
        acc1[i] = fmaf(w[1][r*3+2], w4, acc1[i]);
      }
    }
    // 4 adjacent cg lanes cover channels 16m..16m+15 -> one full 64B line
    *(float4*)(ob + 16 * m + 4 * cg) =
        make_float4(acc0[0], acc0[1], acc0[2], acc0[3]);
    *(float4*)(ob + DTOT + 16 * m + 4 * cg) =
        make_float4(acc1[0], acc1[1], acc1[2], acc1[3]);
  }
}

} // namespace

extern "C" void kernel_launch(void* const* d_in, const int* in_sizes, int n_in,
                              void* d_out, int out_size, void* d_ws, size_t ws_size,
                              hipStream_t stream) {
  const float* q = (const float*)d_in[0];
  const float* k = (const float*)d_in[1];
  const float* v = (const float*)d_in[2];
  float* out = (float*)d_out;

  const int BH = in_sizes[0] / (HD * HW);  // B * 8 heads = 64
  dim3 grid(BH * NPT);
  adda_fwd<<<grid, 256, 0, stream>>>(q, k, v, out);
}

// Round 7
// 62.960 us; speedup vs baseline: 2.0833x; 2.0833x over previous
//
#include <hip/hip_runtime.h>

// ADDA local attention, K=3, dilation=1, head_dim=64.
// q,k,v = [B=8, d=512, H=56, W=56] fp32 (channel-major), out = [B,H,W,512] fp32.
//
// R7 design (R3-R6 lesson: latency-bound on many narrow global loads):
//  - block = (bh, 4-row band). k then v staged into LDS via async
//    global_load_lds dwordx4 (T3 pattern: issue next chunk -> compute -> barrier)
//  - thread = pixel PAIR owning ALL 64 channels -> logits fully in-thread,
//    no reductions, no serial softmax
//  - LDS reads: 4x b32 per (c,row), lane stride 2 floats -> 2-way = free
//  - stores: per chunk one aligned 64B run per pixel (4x float4)
//  - halo rows clamped at staging so LDS always holds finite data;
//    boundary taps zeroed at softmax (zero-padded-unfold semantics)

namespace {

constexpr int HD = 64, HH = 56, WW = 56, HW = HH * WW;
constexpr int CS = HW, DTOT = 512;
constexpr float SCALE = 0.125f;
constexpr int BAND  = 4;             // rows per block
constexpr int NB    = HH / BAND;     // 14 bands
constexpr int HALO  = BAND + 2;      // 6 staged rows
constexpr int CCH   = 16;            // channels per chunk
constexpr int PLANE = HALO * WW;     // 336 floats per channel
constexpr int BUF   = CCH * PLANE;   // 5376 floats = 21.5 KB
constexpr int NF4   = BUF / 4;       // 1344 float4s per chunk
constexpr int NTH   = 128;
constexpr int NPAIR = BAND * WW / 2; // 112 active threads

#define GLOAD_LDS16(g, l)                                        \
  __builtin_amdgcn_global_load_lds(                              \
      (const __attribute__((address_space(1))) void*)(g),        \
      (__attribute__((address_space(3))) void*)(l), 16, 0, 0)

__global__ __launch_bounds__(NTH)
void adda_fwd(const float* __restrict__ qg, const float* __restrict__ kg,
              const float* __restrict__ vg, float* __restrict__ outg) {
  __shared__ __align__(16) float sm[2][BUF];

  const int band = blockIdx.x % NB;
  const int bh   = blockIdx.x / NB;       // b*8 + head
  const int y0   = band * BAND;
  const int t    = (int)threadIdx.x;

  const float* __restrict__ qb = qg + (long)bh * HD * HW;
  const float* __restrict__ kb = kg + (long)bh * HD * HW;
  const float* __restrict__ vb = vg + (long)bh * HD * HW;

  // ---- async staging of one 16-channel chunk (rows y0-1..y0+4, clamped) ----
  auto stage = [&](const float* __restrict__ src, int chunk, int buf) {
#pragma unroll
    for (int rnd = 0; rnd < (NF4 + NTH - 1) / NTH; ++rnd) {
      const int i = rnd * NTH + t;
      if (i < NF4) {
        const int px4 = i % 14;
        const int rr  = (i / 14) % HALO;
        const int c   = i / (14 * HALO);
        int gy = y0 - 1 + rr;
        gy = gy < 0 ? 0 : (gy > HH - 1 ? HH - 1 : gy);
        const float* ga = src + (chunk * CCH + c) * CS + gy * WW + px4 * 4;
        GLOAD_LDS16(ga, (char*)&sm[buf][0] + i * 16);
      }
    }
  };

  // ---- this thread's pixel pair ----
  const bool active = t < NPAIR;
  const int pr    = 2 * t;                   // 0..222
  const int row_l = pr / WW;                 // 0..3
  const int x0    = pr % WW;                 // even
  const int y     = y0 + row_l;
  const int p0    = y0 * WW + pr;            // global pixel index
  const int xm1   = (x0 > 0) ? x0 - 1 : 0;
  const int xp2   = (x0 < WW - 2) ? x0 + 2 : WW - 1;

  float lg[2][9];
#pragma unroll
  for (int e = 0; e < 2; ++e)
#pragma unroll
    for (int n = 0; n < 9; ++n) lg[e][n] = 0.f;

  // ---- pass-1 chunk: accumulate partial logits from LDS k ----
  auto pass1 = [&](int chunk, int buf) {
    if (!active) return;
#pragma unroll
    for (int c = 0; c < CCH; ++c) {
      const float2 qv = *(const float2*)(qb + (chunk * CCH + c) * CS + p0);
      const float* pl = &sm[buf][c * PLANE];
#pragma unroll
      for (int dr = 0; dr < 3; ++dr) {
        const float* rp = pl + (row_l + dr) * WW;
        const float a  = rp[xm1];
        const float b0 = rp[x0];
        const float b1 = rp[x0 + 1];
        const float cc = rp[xp2];
        lg[0][dr*3+0] = fmaf(qv.x, a,  lg[0][dr*3+0]);
        lg[0][dr*3+1] = fmaf(qv.x, b0, lg[0][dr*3+1]);
        lg[0][dr*3+2] = fmaf(qv.x, b1, lg[0][dr*3+2]);
        lg[1][dr*3+0] = fmaf(qv.y, b0, lg[1][dr*3+0]);
        lg[1][dr*3+1] = fmaf(qv.y, b1, lg[1][dr*3+1]);
        lg[1][dr*3+2] = fmaf(qv.y, cc, lg[1][dr*3+2]);
      }
    }
  };

  float w[2][9];

  auto softmax = [&]() {
    if (!active) return;
#pragma unroll
    for (int e = 0; e < 2; ++e) {
      const int xx = x0 + e;
      float lv[9]; bool ok[9];
#pragma unroll
      for (int n = 0; n < 9; ++n) {
        const int dy = n / 3 - 1, dx = n % 3 - 1;
        ok[n] = ((unsigned)(y + dy) < (unsigned)HH) &&
                ((unsigned)(xx + dx) < (unsigned)WW);
        lv[n] = ok[n] ? lg[e][n] * SCALE : 0.f;  // OOB logit = 0 (zero-pad)
      }
      float mx = lv[0];
#pragma unroll
      for (int n = 1; n < 9; ++n) mx = fmaxf(mx, lv[n]);
      float ex[9], sum = 0.f;
#pragma unroll
      for (int n = 0; n < 9; ++n) { ex[n] = __expf(lv[n] - mx); sum += ex[n]; }
      const float inv = 1.f / sum;
#pragma unroll
      for (int n = 0; n < 9; ++n)
        w[e][n] = ok[n] ? ex[n] * inv : 0.f;     // OOB v contributes 0
    }
  };

  const int b = bh >> 3, head = bh & 7;
  float* __restrict__ ob = outg + ((long)b * HW + p0) * DTOT + head * HD;

  // ---- pass-2 chunk: weighted V from LDS, aligned 64B-run stores ----
  auto pass2 = [&](int chunk, int buf) {
    if (!active) return;
#pragma unroll
    for (int c4 = 0; c4 < CCH / 4; ++c4) {
      float o0[4], o1[4];
#pragma unroll
      for (int j = 0; j < 4; ++j) {
        const int c = c4 * 4 + j;
        const float* pl = &sm[buf][c * PLANE];
        float a0 = 0.f, a1 = 0.f;
#pragma unroll
        for (int dr = 0; dr < 3; ++dr) {
          const float* rp = pl + (row_l + dr) * WW;
          const float a  = rp[xm1];
          const float b0 = rp[x0];
          const float b1 = rp[x0 + 1];
          const float cc = rp[xp2];
          a0 = fmaf(w[0][dr*3+0], a,  a0);
          a0 = fmaf(w[0][dr*3+1], b0, a0);
          a0 = fmaf(w[0][dr*3+2], b1, a0);
          a1 = fmaf(w[1][dr*3+0], b0, a1);
          a1 = fmaf(w[1][dr*3+1], b1, a1);
          a1 = fmaf(w[1][dr*3+2], cc, a1);
        }
        o0[j] = a0; o1[j] = a1;
      }
      *(float4*)(ob + chunk * CCH + c4 * 4) =
          make_float4(o0[0], o0[1], o0[2], o0[3]);
      *(float4*)(ob + DTOT + chunk * CCH + c4 * 4) =
          make_float4(o1[0], o1[1], o1[2], o1[3]);
    }
  };

  // ---- pipeline: stage next chunk, compute current, barrier ----
  stage(kb, 0, 0); __syncthreads();
  stage(kb, 1, 1); pass1(0, 0);            __syncthreads();
  stage(kb, 2, 0); pass1(1, 1);            __syncthreads();
  stage(kb, 3, 1); pass1(2, 0);            __syncthreads();
  stage(vb, 0, 0); pass1(3, 1); softmax(); __syncthreads();
  stage(vb, 1, 1); pass2(0, 0);            __syncthreads();
  stage(vb, 2, 0); pass2(1, 1);            __syncthreads();
  stage(vb, 3, 1); pass2(2, 0);            __syncthreads();
                   pass2(3, 1);
}

} // namespace

extern "C" void kernel_launch(void* const* d_in, const int* in_sizes, int n_in,
                              void* d_out, int out_size, void* d_ws, size_t ws_size,
                              hipStream_t stream) {
  const float* q = (const float*)d_in[0];
  const float* k = (const float*)d_in[1];
  const float* v = (const float*)d_in[2];
  float* out = (float*)d_out;

  const int BH = in_sizes[0] / (HD * HW);  // B * 8 heads = 64
  dim3 grid(BH * NB);
  adda_fwd<<<grid, NTH, 0, stream>>>(q, k, v, out);
}

// Round 8
// 54.608 us; speedup vs baseline: 2.4019x; 1.1530x over previous
//
#include <hip/hip_runtime.h>

// ADDA local attention, K=3, dilation=1, head_dim=64.
// q,k,v = [B=8, d=512, H=56, W=56] fp32 (channel-major), out = [B,H,W,512] fp32.
//
// R8 (from R7 counters: latency-bound, occ 11.5%, 2M bank conflicts, masked
// scalar taps):
//  - thread = ONE pixel, 256 threads (224 active = 3.5 waves/block) -> ~2x
//    resident waves vs R7's 128-thread blocks
//  - LDS rows padded: [4 pad][56 data][4 pad], pad word 3 and 60 held at 0.
//    OOB halo rows staged as zeros. => taps rp[0],rp[1],rp[2] off one base
//    (ds_read2-mergeable) and ZERO masking anywhere: OOB logit = 0 and
//    OOB v = 0 exactly, matching zero-padded-unfold semantics.
//  - staging is reg-staged (T14 split): issue global_load_dwordx4 early,
//    ds_write_b128 after the current chunk's compute (padded layout is
//    incompatible with global_load_lds's wave-linear destination).

namespace {

constexpr int HD = 64, HH = 56, WW = 56, HW = HH * WW;
constexpr int CS = HW, DTOT = 512;
constexpr float SCALE = 0.125f;
constexpr int BAND = 4, NB = HH / BAND;   // 14 bands
constexpr int HALO = BAND + 2;            // 6 staged rows
constexpr int CCH  = 16;                  // channels per chunk (4 chunks)
constexpr int PW   = 64;                  // padded row stride (words)
constexpr int ROWS = CCH * HALO;          // 96 rows per buffer
constexpr int BUFW = ROWS * PW;           // 6144 words (24 KB)
constexpr int NF4  = CCH * HALO * 14;     // 1344 f4 per chunk
constexpr int NTH  = 256;
constexpr int NPX  = BAND * WW;           // 224 active threads
constexpr int NRND = (NF4 + NTH - 1) / NTH;  // 6

__global__ __launch_bounds__(NTH, 4)
void adda_fwd(const float* __restrict__ qg, const float* __restrict__ kg,
              const float* __restrict__ vg, float* __restrict__ outg) {
  __shared__ __align__(16) float sm[2][BUFW];   // 49152 B

  const int band = blockIdx.x % NB;
  const int bh   = blockIdx.x / NB;       // b*8 + head
  const int y0   = band * BAND;
  const int t    = (int)threadIdx.x;

  const float* __restrict__ qb = qg + (long)bh * HD * HW;
  const float* __restrict__ kb = kg + (long)bh * HD * HW;
  const float* __restrict__ vb = vg + (long)bh * HD * HW;

  const bool active = t < NPX;
  const int row_l = t / WW;               // 0..3 (active)
  const int x     = t - row_l * WW;
  const int p0    = y0 * WW + t;          // global pixel (active only)

  float4 stg[NRND];

  // ---- issue: global loads (or zeros for OOB halo rows) into registers ----
  auto issue = [&](const float* __restrict__ src, int chunk) {
#pragma unroll
    for (int r = 0; r < NRND; ++r) {
      const int i = r * NTH + t;
      float4 val = make_float4(0.f, 0.f, 0.f, 0.f);
      if (i < NF4) {
        const int rowid = i / 14, j = i - rowid * 14;
        const int c = rowid / HALO, rr = rowid - c * HALO;
        const int gy = y0 - 1 + rr;
        if ((unsigned)gy < (unsigned)HH)
          val = *(const float4*)(src + (chunk * CCH + c) * CS + gy * WW + 4 * j);
      }
      stg[r] = val;
    }
  };

  // ---- write: registers -> padded LDS (per-lane scatter is fine for ds_write)
  auto writeb = [&](int buf) {
#pragma unroll
    for (int r = 0; r < NRND; ++r) {
      const int i = r * NTH + t;
      if (i < NF4) {
        const int rowid = i / 14, j = i - rowid * 14;
        *(float4*)&sm[buf][rowid * PW + 4 + 4 * j] = stg[r];
      }
    }
  };

  // ---- pass 1: logits from LDS k (no masks; pads/OOB rows are zero) ----
  float lg[9];
#pragma unroll
  for (int n = 0; n < 9; ++n) lg[n] = 0.f;

  auto pass1 = [&](int chunk, int buf) {
    if (!active) return;
#pragma unroll
    for (int c = 0; c < CCH; ++c) {
      const float qv = qb[(chunk * CCH + c) * CS + p0];
      const int rbase = (c * HALO + row_l) * PW + x + 3;  // tap x-1
#pragma unroll
      for (int dr = 0; dr < 3; ++dr) {
        const float* rp = &sm[buf][rbase + dr * PW];
        lg[dr * 3 + 0] = fmaf(qv, rp[0], lg[dr * 3 + 0]);
        lg[dr * 3 + 1] = fmaf(qv, rp[1], lg[dr * 3 + 1]);
        lg[dr * 3 + 2] = fmaf(qv, rp[2], lg[dr * 3 + 2]);
      }
    }
  };

  // ---- softmax (unmasked: OOB logits are exactly 0, OOB v exactly 0) ----
  float w[9];
  auto softmax = [&]() {
    if (!active) return;
    float lv[9];
#pragma unroll
    for (int n = 0; n < 9; ++n) lv[n] = lg[n] * SCALE;
    float mx = lv[0];
#pragma unroll
    for (int n = 1; n < 9; ++n) mx = fmaxf(mx, lv[n]);
    float sum = 0.f;
#pragma unroll
    for (int n = 0; n < 9; ++n) { w[n] = __expf(lv[n] - mx); sum += w[n]; }
    const float inv = 1.f / sum;
#pragma unroll
    for (int n = 0; n < 9; ++n) w[n] *= inv;
  };

  // ---- pass 2: weighted V from LDS, 4x float4 stores (full 64B line) ----
  float* __restrict__ ob =
      outg + ((long)(bh >> 3) * HW + p0) * DTOT + (bh & 7) * HD;

  auto pass2 = [&](int chunk, int buf) {
    if (!active) return;
#pragma unroll
    for (int c4 = 0; c4 < CCH / 4; ++c4) {
      float o[4];
#pragma unroll
      for (int u = 0; u < 4; ++u) {
        const int c = c4 * 4 + u;
        const int rbase = (c * HALO + row_l) * PW + x + 3;
        float a = 0.f;
#pragma unroll
        for (int dr = 0; dr < 3; ++dr) {
          const float* rp = &sm[buf][rbase + dr * PW];
          a = fmaf(w[dr * 3 + 0], rp[0], a);
          a = fmaf(w[dr * 3 + 1], rp[1], a);
          a = fmaf(w[dr * 3 + 2], rp[2], a);
        }
        o[u] = a;
      }
      *(float4*)(ob + chunk * CCH + c4 * 4) =
          make_float4(o[0], o[1], o[2], o[3]);
    }
  };

  // ---- prologue: issue chunk k0, zero the pad columns, write, barrier ----
  issue(kb, 0);
  if (t < 2 * ROWS) {           // pad words 3 & 60 of every row, both buffers
    const int buf = t / ROWS, row = t - buf * ROWS;
    sm[buf][row * PW + 3]  = 0.f;
    sm[buf][row * PW + 60] = 0.f;
  }
  writeb(0);
  __syncthreads();

  // ---- pipeline: issue(next) || compute(cur) || write(next), barrier ----
  issue(kb, 1); pass1(0, 0);            writeb(1); __syncthreads();
  issue(kb, 2); pass1(1, 1);            writeb(0); __syncthreads();
  issue(kb, 3); pass1(2, 0);            writeb(1); __syncthreads();
  issue(vb, 0); pass1(3, 1); softmax(); writeb(0); __syncthreads();
  issue(vb, 1); pass2(0, 0);            writeb(1); __syncthreads();
  issue(vb, 2); pass2(1, 1);            writeb(0); __syncthreads();
  issue(vb, 3); pass2(2, 0);            writeb(1); __syncthreads();
                pass2(3, 1);
}

} // namespace

extern "C" void kernel_launch(void* const* d_in, const int* in_sizes, int n_in,
                              void* d_out, int out_size, void* d_ws, size_t ws_size,
                              hipStream_t stream) {
  const float* q = (const float*)d_in[0];
  const float* k = (const float*)d_in[1];
  const float* v = (const float*)d_in[2];
  float* out = (float*)d_out;

  const int BH = in_sizes[0] / (HD * HW);  // B * 8 heads = 64
  dim3 grid(BH * NB);
  adda_fwd<<<grid, NTH, 0, stream>>>(q, k, v, out);
}

// Round 9
// 53.907 us; speedup vs baseline: 2.4331x; 1.0130x over previous
//
#include <hip/hip_runtime.h>

// ADDA local attention, K=3, dilation=1, head_dim=64.
// q,k,v = [B=8, d=512, H=56, W=56] fp32 (channel-major), out = [B,H,W,512] fp32.
//
// R9 (from R8: LDS-pipe instruction count is the wall — 1152 scalar ds_read
// per wave):
//  - thread = pixel PAIR -> taps x0-1..x0+2 read as 2x ds_read_b64 per
//    (channel,row): 3x fewer LDS instrs per pixel
//  - pad-3 row layout ([3 pad][56 data][5 pad], zeros at words 2 & 59):
//    tap pairs are even-aligned (b64-legal) and zero-padded-unfold semantics
//    fall out with NO masking (OOB halo rows staged as zeros)
//  - staging reg-staged (odd LDS offsets -> ds_write2_b32; incompatible with
//    global_load_lds wave-linear dest)
//  - q prefetched one chunk ahead into registers (T14-style issue-early)
//  - 8-channel chunks, 24 KB LDS double-buffered, 16 phases, 1 barrier each

namespace {

constexpr int HD = 64, HH = 56, WW = 56, HW = HH * WW;
constexpr int CS = HW, DTOT = 512;
constexpr float SCALE = 0.125f;
constexpr int BAND = 4, NB = HH / BAND;    // 14 bands
constexpr int HALO = BAND + 2;             // 6 staged rows
constexpr int CCH  = 8;                    // channels per chunk
constexpr int NCHK = HD / CCH;             // 8 chunks (x2 for k and v)
constexpr int PW   = 64;                   // padded row stride (words)
constexpr int ROWS = CCH * HALO;           // 48 rows per buffer
constexpr int BUFW = ROWS * PW;            // 3072 words = 12 KB
constexpr int NTH  = 128;
constexpr int NPAIR = BAND * WW / 2;       // 112 active pair-threads
constexpr int NF4  = CCH * HALO * 14;      // 672 float4 per chunk
constexpr int NRND = (NF4 + NTH - 1) / NTH;  // 6

__global__ __launch_bounds__(NTH)
void adda_fwd(const float* __restrict__ qg, const float* __restrict__ kg,
              const float* __restrict__ vg, float* __restrict__ outg) {
  __shared__ __align__(16) float sm[2][BUFW];   // 24576 B

  const int band = blockIdx.x % NB;
  const int bh   = blockIdx.x / NB;        // b*8 + head
  const int y0   = band * BAND;
  const int t    = (int)threadIdx.x;

  const float* __restrict__ qb = qg + (long)bh * HD * HW;
  const float* __restrict__ kb = kg + (long)bh * HD * HW;
  const float* __restrict__ vb = vg + (long)bh * HD * HW;

  const bool active = t < NPAIR;
  const int row_l = t / (WW / 2);          // 0..3 (active threads)
  const int xp    = t - row_l * (WW / 2);  // pair index 0..27
  const int x0    = 2 * xp;                // even pixel
  const int p0    = (y0 + row_l) * WW + x0;

  // ---- staging: issue global f4 loads (zeros for OOB halo rows) ----
  float4 stg[NRND];
  auto issue = [&](const float* __restrict__ src, int chunk) {
#pragma unroll
    for (int r = 0; r < NRND; ++r) {
      const int i = r * NTH + t;
      float4 val = make_float4(0.f, 0.f, 0.f, 0.f);
      if (i < NF4) {
        const int rowid = i / 14, j = i - rowid * 14;
        const int c = rowid / HALO, rr = rowid - c * HALO;
        const int gy = y0 - 1 + rr;
        if ((unsigned)gy < (unsigned)HH)
          val = *(const float4*)(src + (chunk * CCH + c) * CS + gy * WW + 4 * j);
      }
      stg[r] = val;
    }
  };
  auto writeb = [&](int buf) {
#pragma unroll
    for (int r = 0; r < NRND; ++r) {
      const int i = r * NTH + t;
      if (i < NF4) {
        const int rowid = i / 14, j = i - rowid * 14;
        float* d = &sm[buf][rowid * PW + 3 + 4 * j];  // data word = 3 + x
        d[0] = stg[r].x; d[1] = stg[r].y; d[2] = stg[r].z; d[3] = stg[r].w;
      }
    }
  };

  // ---- q prefetch (one chunk ahead), ping-pong register slabs ----
  float2 qreg[2][CCH];
  auto qload = [&](int slot, int chunk) {
    if (!active) return;
#pragma unroll
    for (int c = 0; c < CCH; ++c)
      qreg[slot][c] = *(const float2*)(qb + (chunk * CCH + c) * CS + p0);
  };

  // ---- pass 1: logits from LDS k (2x b64 taps, no masks) ----
  float lg[2][9];
#pragma unroll
  for (int e = 0; e < 2; ++e)
#pragma unroll
    for (int n = 0; n < 9; ++n) lg[e][n] = 0.f;

  auto pass1 = [&](int buf, int slot) {
    if (!active) return;
#pragma unroll
    for (int c = 0; c < CCH; ++c) {
      const float2 qv = qreg[slot][c];
      const int rbase = (c * HALO + row_l) * PW + x0 + 2;  // tap x0-1
#pragma unroll
      for (int dr = 0; dr < 3; ++dr) {
        const float2 a = *(const float2*)&sm[buf][rbase + dr * PW];      // x0-1,x0
        const float2 b = *(const float2*)&sm[buf][rbase + dr * PW + 2];  // x0+1,x0+2
        lg[0][dr*3+0] = fmaf(qv.x, a.x, lg[0][dr*3+0]);
        lg[0][dr*3+1] = fmaf(qv.x, a.y, lg[0][dr*3+1]);
        lg[0][dr*3+2] = fmaf(qv.x, b.x, lg[0][dr*3+2]);
        lg[1][dr*3+0] = fmaf(qv.y, a.y, lg[1][dr*3+0]);
        lg[1][dr*3+1] = fmaf(qv.y, b.x, lg[1][dr*3+1]);
        lg[1][dr*3+2] = fmaf(qv.y, b.y, lg[1][dr*3+2]);
      }
    }
  };

  // ---- softmax (unmasked: OOB logits exactly 0, OOB v exactly 0) ----
  float w[2][9];
  auto softmax = [&]() {
    if (!active) return;
#pragma unroll
    for (int e = 0; e < 2; ++e) {
      float lv[9];
#pragma unroll
      for (int n = 0; n < 9; ++n) lv[n] = lg[e][n] * SCALE;
      float mx = lv[0];
#pragma unroll
      for (int n = 1; n < 9; ++n) mx = fmaxf(mx, lv[n]);
      float sum = 0.f;
#pragma unroll
      for (int n = 0; n < 9; ++n) { w[e][n] = __expf(lv[n] - mx); sum += w[e][n]; }
      const float inv = 1.f / sum;
#pragma unroll
      for (int n = 0; n < 9; ++n) w[e][n] *= inv;
    }
  };

  // ---- pass 2: weighted V from LDS, 2x float4 stores per pixel ----
  float* __restrict__ ob =
      outg + ((long)(bh >> 3) * HW + p0) * DTOT + (bh & 7) * HD;

  auto pass2 = [&](int chunk, int buf) {
    if (!active) return;
    float o0[CCH], o1[CCH];
#pragma unroll
    for (int c = 0; c < CCH; ++c) { o0[c] = 0.f; o1[c] = 0.f; }
#pragma unroll
    for (int c = 0; c < CCH; ++c) {
      const int rbase = (c * HALO + row_l) * PW + x0 + 2;
#pragma unroll
      for (int dr = 0; dr < 3; ++dr) {
        const float2 a = *(const float2*)&sm[buf][rbase + dr * PW];
        const float2 b = *(const float2*)&sm[buf][rbase + dr * PW + 2];
        o0[c] = fmaf(w[0][dr*3+0], a.x, o0[c]);
        o0[c] = fmaf(w[0][dr*3+1], a.y, o0[c]);
        o0[c] = fmaf(w[0][dr*3+2], b.x, o0[c]);
        o1[c] = fmaf(w[1][dr*3+0], a.y, o1[c]);
        o1[c] = fmaf(w[1][dr*3+1], b.x, o1[c]);
        o1[c] = fmaf(w[1][dr*3+2], b.y, o1[c]);
      }
    }
    *(float4*)(ob + chunk * CCH)     = make_float4(o0[0], o0[1], o0[2], o0[3]);
    *(float4*)(ob + chunk * CCH + 4) = make_float4(o0[4], o0[5], o0[6], o0[7]);
    *(float4*)(ob + DTOT + chunk * CCH)     = make_float4(o1[0], o1[1], o1[2], o1[3]);
    *(float4*)(ob + DTOT + chunk * CCH + 4) = make_float4(o1[4], o1[5], o1[6], o1[7]);
  };

  // ---- prologue ----
  qload(0, 0);
  issue(kb, 0);
  if (t < 2 * ROWS) {   // zero pads (words 2 & 59) once; never overwritten
    const int buf = t / ROWS, row = t - buf * ROWS;
    sm[buf][row * PW + 2]  = 0.f;
    sm[buf][row * PW + 59] = 0.f;
  }
  writeb(0);
  __syncthreads();

  // ---- k phases (8), then v phases (8); one barrier per phase ----
#pragma unroll
  for (int p = 0; p < NCHK; ++p) {
    if (p < NCHK - 1) { issue(kb, p + 1); qload((p + 1) & 1, p + 1); }
    else              { issue(vb, 0); }
    pass1(p & 1, p & 1);
    if (p == NCHK - 1) softmax();
    writeb((p + 1) & 1);
    __syncthreads();
  }
#pragma unroll
  for (int p = 0; p < NCHK; ++p) {
    if (p < NCHK - 1) issue(vb, p + 1);
    pass2(p, p & 1);
    if (p < NCHK - 1) { writeb((p + 1) & 1); __syncthreads(); }
  }
}

} // namespace

extern "C" void kernel_launch(void* const* d_in, const int* in_sizes, int n_in,
                              void* d_out, int out_size, void* d_ws, size_t ws_size,
                              hipStream_t stream) {
  const float* q = (const float*)d_in[0];
  const float* k = (const float*)d_in[1];
  const float* v = (const float*)d_in[2];
  float* out = (float*)d_out;

  const int BH = in_sizes[0] / (HD * HW);  // B * 8 heads = 64
  dim3 grid(BH * NB);
  adda_fwd<<<grid, NTH, 0, stream>>>(q, k, v, out);
}

// Round 11
// 44.334 us; speedup vs baseline: 2.9585x; 1.2159x over previous
//
#include <hip/hip_runtime.h>

// ADDA local attention, K=3, dilation=1, head_dim=64.
// q,k,v = [B=8, d=512, H=56, W=56] fp32 (channel-major), out = [B,H,W,512] fp32.
//
// R11 = R10 with the DPP shift directions corrected.
// ISA semantics (GCN/CDNA, cf. row_shr:1 prefix-scan idiom):
//   wave_shr:1 (0x138): lane i <- lane i-1   => neighbor at x-1
//   wave_shl:1 (0x130): lane i <- lane i+1   => neighbor at x+1
// Wave = one image row (lane = x). Per (c,row): 1 coalesced dword load +
// 2 DPP shifts (VALU pipe) + 3 FMAs. No k/v LDS, no staging, no barriers.
// LDS only for the per-wave store-transpose (full 128B-line output writes).
// Boundary taps masked to exact zero in softmax (= zero-padded unfold).

namespace {

constexpr int HD = 64, HH = 56, WW = 56, HW = HH * WW;
constexpr int CS = HW, DTOT = 512;
constexpr float SCALE = 0.125f;
constexpr int BAND = 4, NB = HH / BAND;  // 4 rows per block (4 waves), 14 bands
constexpr int PXW = 36;                  // padded px stride in transpose LDS

// value of this row at x-1 (lane i <- lane i-1): wave_shr:1 = 0x138
// boundary lane keeps own value (finite; masked to zero later)
__device__ __forceinline__ float tapL(float v) {
  int i = __float_as_int(v);
  return __int_as_float(__builtin_amdgcn_update_dpp(i, i, 0x138, 0xF, 0xF, false));
}
// value of this row at x+1 (lane i <- lane i+1): wave_shl:1 = 0x130
__device__ __forceinline__ float tapR(float v) {
  int i = __float_as_int(v);
  return __int_as_float(__builtin_amdgcn_update_dpp(i, i, 0x130, 0xF, 0xF, false));
}

__global__ __launch_bounds__(256)
void adda_fwd(const float* __restrict__ qg, const float* __restrict__ kg,
              const float* __restrict__ vg, float* __restrict__ outg) {
  __shared__ float sm[4][64 * PXW];      // 36864 B, per-wave regions

  const int band = blockIdx.x % NB;
  const int bh   = blockIdx.x / NB;      // b*8 + head
  const int l    = (int)threadIdx.x & 63;
  const int wv   = (int)threadIdx.x >> 6;
  const int y    = band * BAND + wv;     // this wave's row
  const int x    = l < WW ? l : WW - 1;  // lanes 56-63 clone x=55 (not stored)

  const long base = (long)bh * HD * HW;
  const int gym = y > 0 ? y - 1 : 0;        // clamped row addresses (data for
  const int gyp = y < HH - 1 ? y + 1 : y;   // OOB rows is masked to 0 below)

  const float* __restrict__ qp = qg + base + y * WW + x;
  const float* __restrict__ k0 = kg + base + gym * WW + x;
  const float* __restrict__ k1 = kg + base + y   * WW + x;
  const float* __restrict__ k2 = kg + base + gyp * WW + x;

  // ---- pass 1: logits; 1 load + 2 DPP + 3 FMA per (c,row) ----
  float lg[9];
#pragma unroll
  for (int n = 0; n < 9; ++n) lg[n] = 0.f;

#pragma unroll 8
  for (int c = 0; c < HD; ++c) {
    const float qv = qp[c * CS];
    const float a0 = k0[c * CS], a1 = k1[c * CS], a2 = k2[c * CS];
    lg[0] = fmaf(qv, tapL(a0), lg[0]);   // (dy=-1, dx=-1)
    lg[1] = fmaf(qv, a0,       lg[1]);   // (dy=-1, dx= 0)
    lg[2] = fmaf(qv, tapR(a0), lg[2]);   // (dy=-1, dx=+1)
    lg[3] = fmaf(qv, tapL(a1), lg[3]);
    lg[4] = fmaf(qv, a1,       lg[4]);
    lg[5] = fmaf(qv, tapR(a1), lg[5]);
    lg[6] = fmaf(qv, tapL(a2), lg[6]);
    lg[7] = fmaf(qv, a2,       lg[7]);
    lg[8] = fmaf(qv, tapR(a2), lg[8]);
  }

  // ---- softmax with zero-padded-unfold masking (OOB logit = exact 0) ----
  const bool okt = y > 0, okb = y < HH - 1, okl = x > 0, okr = x < WW - 1;
  const bool ok[9] = {okt && okl, okt, okt && okr,
                      okl,        true, okr,
                      okb && okl, okb, okb && okr};
  float w[9];
  float mx = 0.f;   // zeros (OOB logits) participate in the max
#pragma unroll
  for (int n = 0; n < 9; ++n) { w[n] = ok[n] ? lg[n] * SCALE : 0.f; mx = fmaxf(mx, w[n]); }
  float sum = 0.f;
#pragma unroll
  for (int n = 0; n < 9; ++n) { w[n] = __expf(w[n] - mx); sum += w[n]; }
  const float inv = 1.f / sum;
#pragma unroll
  for (int n = 0; n < 9; ++n) w[n] = ok[n] ? w[n] * inv : 0.f;  // OOB v = 0

  const float* __restrict__ v0 = vg + base + gym * WW + x;
  const float* __restrict__ v1 = vg + base + y   * WW + x;
  const float* __restrict__ v2 = vg + base + gyp * WW + x;

  float* __restrict__ smw = &sm[wv][0];
  float* __restrict__ ob =
      outg + ((long)(bh >> 3) * HW + y * WW) * DTOT + (bh & 7) * HD;

  // ---- pass 2 + store-transpose, in 2 chunks of 32 channels ----
#pragma unroll
  for (int half = 0; half < 2; ++half) {
    const int ch0 = half * 32;
    float o[32];
#pragma unroll
    for (int cc = 0; cc < 32; ++cc) {
      const int c = ch0 + cc;
      const float a0 = v0[c * CS], a1 = v1[c * CS], a2 = v2[c * CS];
      float acc;
      acc = w[0] * tapL(a0);
      acc = fmaf(w[1], a0,       acc);
      acc = fmaf(w[2], tapR(a0), acc);
      acc = fmaf(w[3], tapL(a1), acc);
      acc = fmaf(w[4], a1,       acc);
      acc = fmaf(w[5], tapR(a1), acc);
      acc = fmaf(w[6], tapL(a2), acc);
      acc = fmaf(w[7], a2,       acc);
      acc = fmaf(w[8], tapR(a2), acc);
      o[cc] = acc;
    }
    // lane (=px) dumps its 32 channels; same-wave LDS ops are ordered,
    // so no barrier is needed (per-wave region).
#pragma unroll
    for (int i = 0; i < 8; ++i)
      *(float4*)&smw[l * PXW + i * 4] =
          make_float4(o[i * 4], o[i * 4 + 1], o[i * 4 + 2], o[i * 4 + 3]);
    // cooperative write-out: 56 px x 128B contiguous per px = full lines;
    // 448 float4s over 64 lanes = exactly 7 rounds, all lanes active.
#pragma unroll
    for (int r = 0; r < 7; ++r) {
      const int g = r * 64 + l, px = g >> 3, slot = g & 7;
      const float4 t = *(const float4*)&smw[px * PXW + slot * 4];
      *(float4*)(ob + (long)px * DTOT + ch0 + slot * 4) = t;
    }
  }
}

} // namespace

extern "C" void kernel_launch(void* const* d_in, const int* in_sizes, int n_in,
                              void* d_out, int out_size, void* d_ws, size_t ws_size,
                              hipStream_t stream) {
  const float* q = (const float*)d_in[0];
  const float* k = (const float*)d_in[1];
  const float* v = (const float*)d_in[2];
  float* out = (float*)d_out;

  const int BH = in_sizes[0] / (HD * HW);  // B * 8 heads = 64
  dim3 grid(BH * NB);
  adda_fwd<<<grid, 256, 0, stream>>>(q, k, v, out);
}